// Round 19
// baseline (78.399 us; speedup 1.0000x reference)
//
#include <hip/hip_runtime.h>

// B=16, C=256, H=W=32 -> S=1024, nh=8, hd=32, groups=8.
// color_attn: per-row additive constant before row-softmax -> softmax-invariant -> dropped.
// Softmax max-subtraction dropped (logits O(1), fp32 exp2 safe; softmax shift-invariant).
// log2(e) folded into Q scale; exp via __builtin_amdgcn_exp2f.
// LDS strides for b128-accessed tiles MUST be multiples of 8 shorts (16 B) — round 7.
// PINNED (rounds 9/10/12): MFMA operands from LDS/registers ONLY (V-direct fails
// nondeterministically; setprio exonerated in R18). PINNED (round 13): 4-wave flash.
// PINNED (round 15): 64-wide GEMM tiles. PINNED (round 16): each P LDS address
// written once per tile between barriers.
// This round: reg-prefetch pipelining (flash's proven T3-minimum pattern) ported to
// qkv_mfma and gemm_out — issue kb+1 globals into regs before kb's MFMA; same
// barrier count, same arithmetic order -> bit-exact.

typedef __attribute__((ext_vector_type(8))) short bf16x8;
typedef __attribute__((ext_vector_type(4))) float f32x4;

static __device__ __forceinline__ unsigned cvt_pk(float lo, float hi) {
  unsigned r;
  asm("v_cvt_pk_bf16_f32 %0, %1, %2" : "=v"(r) : "v"(lo), "v"(hi));
  return r;
}

// ---------------- prep: GroupNorm stats (blocks 0-127) + weight conv (128-255) ----------------
__global__ __launch_bounds__(256) void prep_kernel(
    const float* __restrict__ x, float2* __restrict__ stats,
    const float* __restrict__ w0, const float* __restrict__ w1,
    const float* __restrict__ w2, const float* __restrict__ w3,
    short* __restrict__ o0, short* __restrict__ o1,
    short* __restrict__ o2, short* __restrict__ o3) {
  int tid = threadIdx.x;
  if (blockIdx.x < 128) {
    __shared__ float red[8];
    int bg = blockIdx.x;
    const float4* x4 = (const float4*)(x + (size_t)bg * 32 * 1024);
    float s = 0.f, ss = 0.f;
    for (int i = tid; i < 8192; i += 256) {
      float4 vv = x4[i];
      s += (vv.x + vv.y) + (vv.z + vv.w);
      ss += vv.x * vv.x + vv.y * vv.y + vv.z * vv.z + vv.w * vv.w;
    }
#pragma unroll
    for (int o = 32; o > 0; o >>= 1) {
      s += __shfl_down(s, o);
      ss += __shfl_down(ss, o);
    }
    if ((tid & 63) == 0) { red[tid >> 6] = s; red[4 + (tid >> 6)] = ss; }
    __syncthreads();
    if (tid == 0) {
      float S = (red[0] + red[1]) + (red[2] + red[3]);
      float SS = (red[4] + red[5]) + (red[6] + red[7]);
      float mean = S * (1.f / 32768.f);
      float var = SS * (1.f / 32768.f) - mean * mean;
      stats[bg] = make_float2(mean, rsqrtf(var + 1e-5f));
    }
  } else {
    int idx = blockIdx.x - 128;
    int sel = idx >> 5, blk = idx & 31;
    const float* src = sel == 0 ? w0 : sel == 1 ? w1 : sel == 2 ? w2 : w3;
    short* dst = sel == 0 ? o0 : sel == 1 ? o1 : sel == 2 ? o2 : o3;
    int i = (blk * 256 + tid) * 8;
    float4 a = *(const float4*)(src + i);
    float4 b = *(const float4*)(src + i + 4);
    uint4 r;
    r.x = cvt_pk(a.x, a.y);
    r.y = cvt_pk(a.z, a.w);
    r.z = cvt_pk(b.x, b.y);
    r.w = cvt_pk(b.z, b.w);
    *(uint4*)(dst + i) = r;
  }
}

// ---------------- fused GN + QKV MFMA GEMM (64x64 tiles, reg-prefetch pipelined) ----------------
__global__ __launch_bounds__(256, 4) void qkv_mfma(
    const float* __restrict__ x, const float2* __restrict__ stats,
    const float* __restrict__ gnw, const float* __restrict__ gnb,
    const short* __restrict__ Wq, const short* __restrict__ Wk,
    const short* __restrict__ Wv,
    const float* __restrict__ bq, const float* __restrict__ bk,
    const float* __restrict__ bv, short* __restrict__ outq,
    short* __restrict__ outk, short* __restrict__ outvt, float scaleq) {
  __shared__ __align__(16) char smem[20480];
  short* As = (short*)smem;  // A + 3 W tiles, each 64*40 shorts, stride 80 B
  int tid = threadIdx.x;
  int m0 = blockIdx.x * 64, n0 = blockIdx.y * 64;
  int w = tid >> 6, lane = tid & 63, g = lane >> 4, c = lane & 15;
  int wm = w >> 1, wn = w & 1;
  int srow = tid >> 2, sk = (tid & 3) * 8;
  int bsmp = m0 >> 10, s0 = m0 & 1023;
  int c2 = tid & 15, sg = tid >> 4;
  const float4* xb = (const float4*)(x + (size_t)(bsmp * 256) * 1024);
  unsigned* A32 = (unsigned*)As;
  f32x4 accq[2][2], acck[2][2], accv[2][2];
#pragma unroll
  for (int i = 0; i < 2; ++i)
#pragma unroll
    for (int j = 0; j < 2; ++j) {
      accq[i][j] = (f32x4){0.f, 0.f, 0.f, 0.f};
      acck[i][j] = (f32x4){0.f, 0.f, 0.f, 0.f};
      accv[i][j] = (f32x4){0.f, 0.f, 0.f, 0.f};
    }
  // prologue: prefetch tile 0 into registers
  float a0, a1, b0v, b1v;
  float4 u, v;
  bf16x8 wqr, wkr, wvr;
  {
    float2 st = stats[bsmp * 8];
    int ch0 = c2 * 2;
    a0 = gnw[ch0] * st.y; b0v = gnb[ch0] - st.x * a0;
    a1 = gnw[ch0 + 1] * st.y; b1v = gnb[ch0 + 1] - st.x * a1;
    u = xb[(size_t)ch0 * 256 + (s0 >> 2) + sg];
    v = xb[(size_t)(ch0 + 1) * 256 + (s0 >> 2) + sg];
    wqr = *(const bf16x8*)(Wq + (size_t)(n0 + srow) * 256 + sk);
    wkr = *(const bf16x8*)(Wk + (size_t)(n0 + srow) * 256 + sk);
    wvr = *(const bf16x8*)(Wv + (size_t)(n0 + srow) * 256 + sk);
  }
  for (int kb = 0; kb < 8; ++kb) {
    // stage current tile from registers
    {
      int r0 = (sg * 4) * 20 + c2;
      A32[r0]      = cvt_pk(u.x * a0 + b0v, v.x * a1 + b1v);
      A32[r0 + 20] = cvt_pk(u.y * a0 + b0v, v.y * a1 + b1v);
      A32[r0 + 40] = cvt_pk(u.z * a0 + b0v, v.z * a1 + b1v);
      A32[r0 + 60] = cvt_pk(u.w * a0 + b0v, v.w * a1 + b1v);
    }
    *(bf16x8*)(As + 2560 + srow * 40 + sk) = wqr;
    *(bf16x8*)(As + 5120 + srow * 40 + sk) = wkr;
    *(bf16x8*)(As + 7680 + srow * 40 + sk) = wvr;
    __syncthreads();
    // issue next tile's global loads (hidden under this tile's MFMA)
    if (kb < 7) {
      float2 st = stats[bsmp * 8 + kb + 1];
      int chn = (kb + 1) * 32 + c2 * 2;
      a0 = gnw[chn] * st.y; b0v = gnb[chn] - st.x * a0;
      a1 = gnw[chn + 1] * st.y; b1v = gnb[chn + 1] - st.x * a1;
      u = xb[(size_t)chn * 256 + (s0 >> 2) + sg];
      v = xb[(size_t)(chn + 1) * 256 + (s0 >> 2) + sg];
      wqr = *(const bf16x8*)(Wq + (size_t)(n0 + srow) * 256 + (kb + 1) * 32 + sk);
      wkr = *(const bf16x8*)(Wk + (size_t)(n0 + srow) * 256 + (kb + 1) * 32 + sk);
      wvr = *(const bf16x8*)(Wv + (size_t)(n0 + srow) * 256 + (kb + 1) * 32 + sk);
    }
    bf16x8 af[2], wfq[2], wfk[2], wfv[2];
#pragma unroll
    for (int i = 0; i < 2; ++i)
      af[i] = *(const bf16x8*)(As + (wm * 32 + i * 16 + c) * 40 + g * 8);
#pragma unroll
    for (int j = 0; j < 2; ++j) {
      int rr = (wn * 32 + j * 16 + c) * 40 + g * 8;
      wfq[j] = *(const bf16x8*)(As + 2560 + rr);
      wfk[j] = *(const bf16x8*)(As + 5120 + rr);
      wfv[j] = *(const bf16x8*)(As + 7680 + rr);
    }
#pragma unroll
    for (int i = 0; i < 2; ++i)
#pragma unroll
      for (int j = 0; j < 2; ++j) {
        accq[i][j] = __builtin_amdgcn_mfma_f32_16x16x32_bf16(wfq[j], af[i], accq[i][j], 0, 0, 0);
        acck[i][j] = __builtin_amdgcn_mfma_f32_16x16x32_bf16(wfk[j], af[i], acck[i][j], 0, 0, 0);
        accv[i][j] = __builtin_amdgcn_mfma_f32_16x16x32_bf16(af[i], wfv[j], accv[i][j], 0, 0, 0);
      }
    __syncthreads();
  }
  short* Tb = (short*)smem;  // [64][72] (144 B row pitch = 9*16, b128-safe)
  int mrd = tid >> 2, ncol = (tid & 3) * 16;
  // --- Q (swapped acc: col c = spatial, rows 4g+r = out-channel) ---
#pragma unroll
  for (int i = 0; i < 2; ++i)
#pragma unroll
    for (int j = 0; j < 2; ++j) {
      float4 b4 = *(const float4*)&bq[n0 + wn * 32 + j * 16 + 4 * g];
      float v0 = (accq[i][j][0] + b4.x) * scaleq;
      float v1 = (accq[i][j][1] + b4.y) * scaleq;
      float v2 = (accq[i][j][2] + b4.z) * scaleq;
      float v3 = (accq[i][j][3] + b4.w) * scaleq;
      *(uint2*)(Tb + (wm * 32 + i * 16 + c) * 72 + wn * 32 + j * 16 + 4 * g) =
          make_uint2(cvt_pk(v0, v1), cvt_pk(v2, v3));
    }
  __syncthreads();
  {
    bf16x8 r0 = *(const bf16x8*)(Tb + mrd * 72 + ncol);
    bf16x8 r1 = *(const bf16x8*)(Tb + mrd * 72 + ncol + 8);
    short* dst = outq + (size_t)(m0 + mrd) * 256 + n0 + ncol;
    *(bf16x8*)dst = r0;
    *(bf16x8*)(dst + 8) = r1;
  }
  __syncthreads();
  // --- K ---
#pragma unroll
  for (int i = 0; i < 2; ++i)
#pragma unroll
    for (int j = 0; j < 2; ++j) {
      float4 b4 = *(const float4*)&bk[n0 + wn * 32 + j * 16 + 4 * g];
      float v0 = acck[i][j][0] + b4.x;
      float v1 = acck[i][j][1] + b4.y;
      float v2 = acck[i][j][2] + b4.z;
      float v3 = acck[i][j][3] + b4.w;
      *(uint2*)(Tb + (wm * 32 + i * 16 + c) * 72 + wn * 32 + j * 16 + 4 * g) =
          make_uint2(cvt_pk(v0, v1), cvt_pk(v2, v3));
    }
  __syncthreads();
  {
    bf16x8 r0 = *(const bf16x8*)(Tb + mrd * 72 + ncol);
    bf16x8 r1 = *(const bf16x8*)(Tb + mrd * 72 + ncol + 8);
    short* dst = outk + (size_t)(m0 + mrd) * 256 + n0 + ncol;
    *(bf16x8*)dst = r0;
    *(bf16x8*)(dst + 8) = r1;
  }
  __syncthreads();
  // --- V (normal acc) -> vt[d][s] ---
#pragma unroll
  for (int i = 0; i < 2; ++i)
#pragma unroll
    for (int j = 0; j < 2; ++j) {
      float bvv = bv[n0 + wn * 32 + j * 16 + c];
      float v0 = accv[i][j][0] + bvv;
      float v1 = accv[i][j][1] + bvv;
      float v2 = accv[i][j][2] + bvv;
      float v3 = accv[i][j][3] + bvv;
      *(uint2*)(Tb + (wn * 32 + j * 16 + c) * 72 + wm * 32 + i * 16 + 4 * g) =
          make_uint2(cvt_pk(v0, v1), cvt_pk(v2, v3));
    }
  __syncthreads();
  {
    bf16x8 r0 = *(const bf16x8*)(Tb + mrd * 72 + ncol);
    bf16x8 r1 = *(const bf16x8*)(Tb + mrd * 72 + ncol + 8);
    short* dst = outvt + (size_t)(bsmp * 256 + n0 + mrd) * 1024 + s0 + ncol;
    *(bf16x8*)dst = r0;
    *(bf16x8*)(dst + 8) = r1;
  }
}

// ---------------- MFMA flash attention (4 waves; pinned structure + XCD swizzle + setprio) --------
#define KSTR 40
#define VSTR 72
#define PSTR 72

__global__ __launch_bounds__(256, 4) void flash_mfma(
    const short* __restrict__ q, const short* __restrict__ k,
    const short* __restrict__ vt, short* __restrict__ out) {
  __shared__ short Ks[2][64 * KSTR];
  __shared__ short Vts[2][32 * VSTR];
  __shared__ short Ps[4 * 32 * PSTR];
  int id = blockIdx.x;
  int swz = (id & 7) * 128 + (id >> 3);   // bijective on [0,1024)
  int bh = swz >> 3, qt = swz & 7;
  int b = bh >> 3, h = bh & 7;
  int tid = threadIdx.x;
  int w = tid >> 6, lane = tid & 63, g = lane >> 4, c = lane & 15;
  short* Psw = Ps + w * 32 * PSTR;
  const size_t qrow0 = (size_t)b * 1024 + qt * 128 + w * 32;
  const int hoff = h * 32;
  bf16x8 aq[2];
#pragma unroll
  for (int mt = 0; mt < 2; ++mt)
    aq[mt] = *(const bf16x8*)(q + (qrow0 + mt * 16 + c) * 256 + hoff + g * 8);
  bf16x8 ones;
#pragma unroll
  for (int i = 0; i < 8; ++i) ones[i] = (short)0x3F80;
  f32x4 o_acc[2][2], accl[2];
#pragma unroll
  for (int mt = 0; mt < 2; ++mt) {
    accl[mt] = (f32x4){0.f, 0.f, 0.f, 0.f};
#pragma unroll
    for (int nt = 0; nt < 2; ++nt) o_acc[mt][nt] = (f32x4){0.f, 0.f, 0.f, 0.f};
  }
  const int kr = tid >> 2, kch = (tid & 3) * 8;
  const int vr = tid >> 3, vch = (tid & 7) * 8;
  const short* kbase = k + ((size_t)b * 1024) * 256 + hoff;
  const short* vbase = vt + (((size_t)b * 8 + h) * 32) * 1024;
  {
    bf16x8 k0 = *(const bf16x8*)(kbase + (size_t)kr * 256 + kch);
    bf16x8 v0 = *(const bf16x8*)(vbase + (size_t)vr * 1024 + vch);
    *(bf16x8*)(&Ks[0][kr * KSTR + kch]) = k0;
    *(bf16x8*)(&Vts[0][vr * VSTR + vch]) = v0;
  }
  __syncthreads();
  int cur = 0;
#pragma unroll 2
  for (int t = 0; t < 16; ++t) {
    bf16x8 kN, vN;
    if (t < 15) {
      kN = *(const bf16x8*)(kbase + (size_t)((t + 1) * 64 + kr) * 256 + kch);
      vN = *(const bf16x8*)(vbase + (size_t)vr * 1024 + (t + 1) * 64 + vch);
    }
    bf16x8 bk4[4];
#pragma unroll
    for (int kt = 0; kt < 4; ++kt)
      bk4[kt] = *(const bf16x8*)(&Ks[cur][(kt * 16 + c) * KSTR + g * 8]);
    f32x4 sc[2][4];
    __builtin_amdgcn_s_setprio(1);
#pragma unroll
    for (int mt = 0; mt < 2; ++mt)
#pragma unroll
      for (int kt = 0; kt < 4; ++kt)
        sc[mt][kt] = __builtin_amdgcn_mfma_f32_16x16x32_bf16(
            bk4[kt], aq[mt], (f32x4){0.f, 0.f, 0.f, 0.f}, 0, 0, 0);
    __builtin_amdgcn_s_setprio(0);
#pragma unroll
    for (int mt = 0; mt < 2; ++mt)
#pragma unroll
      for (int kt = 0; kt < 4; ++kt) {
        float p0 = __builtin_amdgcn_exp2f(sc[mt][kt][0]);
        float p1 = __builtin_amdgcn_exp2f(sc[mt][kt][1]);
        float p2 = __builtin_amdgcn_exp2f(sc[mt][kt][2]);
        float p3 = __builtin_amdgcn_exp2f(sc[mt][kt][3]);
        *(uint2*)(Psw + (mt * 16 + c) * PSTR + kt * 16 + 4 * g) =
            make_uint2(cvt_pk(p0, p1), cvt_pk(p2, p3));
      }
#pragma unroll
    for (int jt = 0; jt < 2; ++jt) {
      bf16x8 av[2], bp[2];
#pragma unroll
      for (int nt = 0; nt < 2; ++nt)
        av[nt] = *(const bf16x8*)(&Vts[cur][(nt * 16 + c) * VSTR + jt * 32 + g * 8]);
#pragma unroll
      for (int mt = 0; mt < 2; ++mt)
        bp[mt] = *(const bf16x8*)(Psw + (mt * 16 + c) * PSTR + jt * 32 + g * 8);
      __builtin_amdgcn_s_setprio(1);
#pragma unroll
      for (int mt = 0; mt < 2; ++mt) {
#pragma unroll
        for (int nt = 0; nt < 2; ++nt)
          o_acc[mt][nt] = __builtin_amdgcn_mfma_f32_16x16x32_bf16(
              av[nt], bp[mt], o_acc[mt][nt], 0, 0, 0);
        accl[mt] = __builtin_amdgcn_mfma_f32_16x16x32_bf16(ones, bp[mt], accl[mt], 0, 0, 0);
      }
      __builtin_amdgcn_s_setprio(0);
    }
    if (t < 15) {
      *(bf16x8*)(&Ks[cur ^ 1][kr * KSTR + kch]) = kN;
      *(bf16x8*)(&Vts[cur ^ 1][vr * VSTR + vch]) = vN;
      __syncthreads();
      cur ^= 1;
    }
  }
#pragma unroll
  for (int mt = 0; mt < 2; ++mt) {
    float linv = 1.0f / accl[mt][0];
#pragma unroll
    for (int nt = 0; nt < 2; ++nt) {
      float v0 = o_acc[mt][nt][0] * linv;
      float v1 = o_acc[mt][nt][1] * linv;
      float v2 = o_acc[mt][nt][2] * linv;
      float v3 = o_acc[mt][nt][3] * linv;
      *(uint2*)(out + (qrow0 + mt * 16 + c) * 256 + hoff + nt * 16 + 4 * g) =
          make_uint2(cvt_pk(v0, v1), cvt_pk(v2, v3));
    }
  }
}

// ---------------- out-projection GEMM (64x64 tiles), m-major grid, reg-prefetch -----------
__global__ __launch_bounds__(256) void gemm_out(
    const short* __restrict__ A, const short* __restrict__ W,
    const float* __restrict__ bias, float* __restrict__ out) {
  __shared__ __align__(16) char smem[10240];
  short* As = (short*)smem;            // 64*40 shorts = 5120 B
  short* Ws = (short*)(smem + 5120);
  int tid = threadIdx.x;
  int m0 = blockIdx.x * 64, n0 = blockIdx.y * 64;
  int w = tid >> 6, lane = tid & 63, g = lane >> 4, c = lane & 15;
  int wm = w >> 1, wn = w & 1;
  int srow = tid >> 2, sk = (tid & 3) * 8;
  f32x4 acc[2][2];
#pragma unroll
  for (int i = 0; i < 2; ++i)
#pragma unroll
    for (int j = 0; j < 2; ++j) acc[i][j] = (f32x4){0.f, 0.f, 0.f, 0.f};
  bf16x8 aR = *(const bf16x8*)(A + (size_t)(m0 + srow) * 256 + sk);
  bf16x8 wR = *(const bf16x8*)(W + (size_t)(n0 + srow) * 256 + sk);
  for (int kb = 0; kb < 8; ++kb) {
    *(bf16x8*)(As + srow * 40 + sk) = aR;
    *(bf16x8*)(Ws + srow * 40 + sk) = wR;
    __syncthreads();
    if (kb < 7) {
      aR = *(const bf16x8*)(A + (size_t)(m0 + srow) * 256 + (kb + 1) * 32 + sk);
      wR = *(const bf16x8*)(W + (size_t)(n0 + srow) * 256 + (kb + 1) * 32 + sk);
    }
    bf16x8 af[2], wf[2];
#pragma unroll
    for (int i = 0; i < 2; ++i)
      af[i] = *(const bf16x8*)(As + (wm * 32 + i * 16 + c) * 40 + g * 8);
#pragma unroll
    for (int j = 0; j < 2; ++j)
      wf[j] = *(const bf16x8*)(Ws + (wn * 32 + j * 16 + c) * 40 + g * 8);
#pragma unroll
    for (int i = 0; i < 2; ++i)
#pragma unroll
      for (int j = 0; j < 2; ++j)
        acc[i][j] = __builtin_amdgcn_mfma_f32_16x16x32_bf16(af[i], wf[j], acc[i][j], 0, 0, 0);
    __syncthreads();
  }
  int bsmp = m0 >> 10, s0 = m0 & 1023;
  float* Tf = (float*)smem;  // [32][68] XOR-swizzled
  for (int half = 0; half < 2; ++half) {
    __syncthreads();
    if (wn == half) {
#pragma unroll
      for (int j = 0; j < 2; ++j) {
        float bvh = bias[n0 + half * 32 + j * 16 + c];
        int nl = j * 16 + c;
#pragma unroll
        for (int i = 0; i < 2; ++i)
#pragma unroll
          for (int r = 0; r < 4; ++r)
            Tf[nl * 68 + ((wm * 32 + i * 16 + 4 * g + r) ^ ((nl & 7) << 2))] =
                acc[i][j][r] + bvh;
      }
    }
    __syncthreads();
    int n = tid >> 3, mc = (tid & 7) * 8;
    float4 v0 = *(const float4*)(Tf + n * 68 + ((mc + 0) ^ ((n & 7) << 2)));
    float4 v1 = *(const float4*)(Tf + n * 68 + ((mc + 4) ^ ((n & 7) << 2)));
    float* dst = out + ((size_t)(bsmp * 256) + n0 + half * 32 + n) * 1024 + s0 + mc;
    *(float4*)dst = v0;
    *(float4*)(dst + 4) = v1;
  }
}

extern "C" void kernel_launch(void* const* d_in, const int* in_sizes, int n_in,
                              void* d_out, int out_size, void* d_ws, size_t ws_size,
                              hipStream_t stream) {
  const float* x   = (const float*)d_in[0];
  const float* wq  = (const float*)d_in[1];
  const float* bq  = (const float*)d_in[2];
  const float* wk  = (const float*)d_in[3];
  const float* bk  = (const float*)d_in[4];
  const float* wv  = (const float*)d_in[5];
  const float* bv  = (const float*)d_in[6];
  const float* wo  = (const float*)d_in[7];
  const float* bo  = (const float*)d_in[8];
  const float* gnw = (const float*)d_in[9];
  const float* gnb = (const float*)d_in[10];
  float* out = (float*)d_out;

  const size_t NE = (size_t)16 * 1024 * 256;  // 4194304
  short* sw  = (short*)d_ws;
  float2* stats = (float2*)sw;  // 128 pairs
  short* qb  = sw + NE;         // bf16, pre-scaled by hd^-0.5*log2e
  short* kb  = sw + 2 * NE;
  short* vtb = sw + 3 * NE;     // bf16 [(b*8+h)*32+d][S]
  short* ao  = sw + 4 * NE;     // bf16 attn out [B*S][C]
  short* wqb = sw + 5 * NE;
  short* wkb = wqb + 65536;
  short* wvb = wkb + 65536;
  short* wob = wvb + 65536;

  const float SCALE_Q = (float)(0.17677669529663689 * 1.4426950408889634);
  dim3 blk(256);
  prep_kernel<<<dim3(256), blk, 0, stream>>>(x, stats, wq, wk, wv, wo,
                                             wqb, wkb, wvb, wob);
  qkv_mfma<<<dim3(256, 4), blk, 0, stream>>>(x, stats, gnw, gnb, wqb, wkb, wvb,
                                             bq, bk, bv, qb, kb, vtb, SCALE_Q);
  flash_mfma<<<dim3(1024), blk, 0, stream>>>(qb, kb, vtb, ao);
  gemm_out<<<dim3(256, 4), blk, 0, stream>>>(ao, wob, bo, out);
}

// Round 20
// 73.732 us; speedup vs baseline: 1.0633x; 1.0633x over previous
//
#include <hip/hip_runtime.h>

// B=16, C=256, H=W=32 -> S=1024, nh=8, hd=32, groups=8.
// color_attn: per-row additive constant before row-softmax -> softmax-invariant -> dropped.
// Softmax max-subtraction dropped (logits O(1), fp32 exp2 safe; softmax shift-invariant).
// log2(e) folded into Q scale; exp via __builtin_amdgcn_exp2f.
// LDS strides for b128-accessed tiles MUST be multiples of 8 shorts (16 B) — round 7.
// PINNED (rounds 9/10/12): MFMA operands from LDS/registers ONLY (V-direct fails
// nondeterministically; setprio exonerated in R18). PINNED (round 13): 4-wave flash.
// PINNED (round 15): 64-wide GEMM tiles. PINNED (round 16): each P LDS address
// written once per tile between barriers. PINNED (round 19): reg-prefetch in GEMMs
// is neutral (TLP already covers staging latency at 4 blocks/CU).
// This round: gn_stats split into 4 partial-sum blocks per (b,g) (512+128 = 640
// blocks = 2.5/CU vs 0.5/CU) — partials combined deterministically inside qkv.

typedef __attribute__((ext_vector_type(8))) short bf16x8;
typedef __attribute__((ext_vector_type(4))) float f32x4;

static __device__ __forceinline__ unsigned cvt_pk(float lo, float hi) {
  unsigned r;
  asm("v_cvt_pk_bf16_f32 %0, %1, %2" : "=v"(r) : "v"(lo), "v"(hi));
  return r;
}

// ---------------- prep: GN partial sums (blocks 0-511, 4 per bg) + wconv (512-639) ------------
__global__ __launch_bounds__(256) void prep_kernel(
    const float* __restrict__ x, float2* __restrict__ statsp,
    const float* __restrict__ w0, const float* __restrict__ w1,
    const float* __restrict__ w2, const float* __restrict__ w3,
    short* __restrict__ o0, short* __restrict__ o1,
    short* __restrict__ o2, short* __restrict__ o3) {
  int tid = threadIdx.x;
  if (blockIdx.x < 512) {
    __shared__ float red[8];
    int bg = blockIdx.x >> 2, qtr = blockIdx.x & 3;
    const float4* x4 = (const float4*)(x + (size_t)bg * 32 * 1024);
    float s = 0.f, ss = 0.f;
#pragma unroll
    for (int p = 0; p < 8; ++p) {
      float4 vv = x4[qtr * 2048 + p * 256 + tid];
      s += (vv.x + vv.y) + (vv.z + vv.w);
      ss += vv.x * vv.x + vv.y * vv.y + vv.z * vv.z + vv.w * vv.w;
    }
#pragma unroll
    for (int o = 32; o > 0; o >>= 1) {
      s += __shfl_down(s, o);
      ss += __shfl_down(ss, o);
    }
    if ((tid & 63) == 0) { red[tid >> 6] = s; red[4 + (tid >> 6)] = ss; }
    __syncthreads();
    if (tid == 0) {
      float S = (red[0] + red[1]) + (red[2] + red[3]);
      float SS = (red[4] + red[5]) + (red[6] + red[7]);
      statsp[bg * 4 + qtr] = make_float2(S, SS);
    }
  } else {
    int idx = blockIdx.x - 512;
    int sel = idx >> 5, blk = idx & 31;
    const float* src = sel == 0 ? w0 : sel == 1 ? w1 : sel == 2 ? w2 : w3;
    short* dst = sel == 0 ? o0 : sel == 1 ? o1 : sel == 2 ? o2 : o3;
    int i = (blk * 256 + tid) * 8;
    float4 a = *(const float4*)(src + i);
    float4 b = *(const float4*)(src + i + 4);
    uint4 r;
    r.x = cvt_pk(a.x, a.y);
    r.y = cvt_pk(a.z, a.w);
    r.z = cvt_pk(b.x, b.y);
    r.w = cvt_pk(b.z, b.w);
    *(uint4*)(dst + i) = r;
  }
}

static __device__ __forceinline__ float2 combine_stats(const float2* __restrict__ sp,
                                                       int bgidx) {
  float2 p0 = sp[bgidx * 4 + 0];
  float2 p1 = sp[bgidx * 4 + 1];
  float2 p2 = sp[bgidx * 4 + 2];
  float2 p3 = sp[bgidx * 4 + 3];
  float S = (p0.x + p1.x) + (p2.x + p3.x);
  float SS = (p0.y + p1.y) + (p2.y + p3.y);
  float mean = S * (1.f / 32768.f);
  float var = SS * (1.f / 32768.f) - mean * mean;
  return make_float2(mean, rsqrtf(var + 1e-5f));
}

// ---------------- fused GN + QKV MFMA GEMM (64x64 tiles, reg-prefetch pipelined) ----------------
__global__ __launch_bounds__(256, 4) void qkv_mfma(
    const float* __restrict__ x, const float2* __restrict__ statsp,
    const float* __restrict__ gnw, const float* __restrict__ gnb,
    const short* __restrict__ Wq, const short* __restrict__ Wk,
    const short* __restrict__ Wv,
    const float* __restrict__ bq, const float* __restrict__ bk,
    const float* __restrict__ bv, short* __restrict__ outq,
    short* __restrict__ outk, short* __restrict__ outvt, float scaleq) {
  __shared__ __align__(16) char smem[20480];
  short* As = (short*)smem;  // A + 3 W tiles, each 64*40 shorts, stride 80 B
  int tid = threadIdx.x;
  int m0 = blockIdx.x * 64, n0 = blockIdx.y * 64;
  int w = tid >> 6, lane = tid & 63, g = lane >> 4, c = lane & 15;
  int wm = w >> 1, wn = w & 1;
  int srow = tid >> 2, sk = (tid & 3) * 8;
  int bsmp = m0 >> 10, s0 = m0 & 1023;
  int c2 = tid & 15, sg = tid >> 4;
  const float4* xb = (const float4*)(x + (size_t)(bsmp * 256) * 1024);
  unsigned* A32 = (unsigned*)As;
  f32x4 accq[2][2], acck[2][2], accv[2][2];
#pragma unroll
  for (int i = 0; i < 2; ++i)
#pragma unroll
    for (int j = 0; j < 2; ++j) {
      accq[i][j] = (f32x4){0.f, 0.f, 0.f, 0.f};
      acck[i][j] = (f32x4){0.f, 0.f, 0.f, 0.f};
      accv[i][j] = (f32x4){0.f, 0.f, 0.f, 0.f};
    }
  // prologue: prefetch tile 0 into registers
  float a0, a1, b0v, b1v;
  float4 u, v;
  bf16x8 wqr, wkr, wvr;
  {
    float2 st = combine_stats(statsp, bsmp * 8);
    int ch0 = c2 * 2;
    a0 = gnw[ch0] * st.y; b0v = gnb[ch0] - st.x * a0;
    a1 = gnw[ch0 + 1] * st.y; b1v = gnb[ch0 + 1] - st.x * a1;
    u = xb[(size_t)ch0 * 256 + (s0 >> 2) + sg];
    v = xb[(size_t)(ch0 + 1) * 256 + (s0 >> 2) + sg];
    wqr = *(const bf16x8*)(Wq + (size_t)(n0 + srow) * 256 + sk);
    wkr = *(const bf16x8*)(Wk + (size_t)(n0 + srow) * 256 + sk);
    wvr = *(const bf16x8*)(Wv + (size_t)(n0 + srow) * 256 + sk);
  }
  for (int kb = 0; kb < 8; ++kb) {
    // stage current tile from registers
    {
      int r0 = (sg * 4) * 20 + c2;
      A32[r0]      = cvt_pk(u.x * a0 + b0v, v.x * a1 + b1v);
      A32[r0 + 20] = cvt_pk(u.y * a0 + b0v, v.y * a1 + b1v);
      A32[r0 + 40] = cvt_pk(u.z * a0 + b0v, v.z * a1 + b1v);
      A32[r0 + 60] = cvt_pk(u.w * a0 + b0v, v.w * a1 + b1v);
    }
    *(bf16x8*)(As + 2560 + srow * 40 + sk) = wqr;
    *(bf16x8*)(As + 5120 + srow * 40 + sk) = wkr;
    *(bf16x8*)(As + 7680 + srow * 40 + sk) = wvr;
    __syncthreads();
    // issue next tile's global loads (hidden under this tile's MFMA)
    if (kb < 7) {
      float2 st = combine_stats(statsp, bsmp * 8 + kb + 1);
      int chn = (kb + 1) * 32 + c2 * 2;
      a0 = gnw[chn] * st.y; b0v = gnb[chn] - st.x * a0;
      a1 = gnw[chn + 1] * st.y; b1v = gnb[chn + 1] - st.x * a1;
      u = xb[(size_t)chn * 256 + (s0 >> 2) + sg];
      v = xb[(size_t)(chn + 1) * 256 + (s0 >> 2) + sg];
      wqr = *(const bf16x8*)(Wq + (size_t)(n0 + srow) * 256 + (kb + 1) * 32 + sk);
      wkr = *(const bf16x8*)(Wk + (size_t)(n0 + srow) * 256 + (kb + 1) * 32 + sk);
      wvr = *(const bf16x8*)(Wv + (size_t)(n0 + srow) * 256 + (kb + 1) * 32 + sk);
    }
    bf16x8 af[2], wfq[2], wfk[2], wfv[2];
#pragma unroll
    for (int i = 0; i < 2; ++i)
      af[i] = *(const bf16x8*)(As + (wm * 32 + i * 16 + c) * 40 + g * 8);
#pragma unroll
    for (int j = 0; j < 2; ++j) {
      int rr = (wn * 32 + j * 16 + c) * 40 + g * 8;
      wfq[j] = *(const bf16x8*)(As + 2560 + rr);
      wfk[j] = *(const bf16x8*)(As + 5120 + rr);
      wfv[j] = *(const bf16x8*)(As + 7680 + rr);
    }
#pragma unroll
    for (int i = 0; i < 2; ++i)
#pragma unroll
      for (int j = 0; j < 2; ++j) {
        accq[i][j] = __builtin_amdgcn_mfma_f32_16x16x32_bf16(wfq[j], af[i], accq[i][j], 0, 0, 0);
        acck[i][j] = __builtin_amdgcn_mfma_f32_16x16x32_bf16(wfk[j], af[i], acck[i][j], 0, 0, 0);
        accv[i][j] = __builtin_amdgcn_mfma_f32_16x16x32_bf16(af[i], wfv[j], accv[i][j], 0, 0, 0);
      }
    __syncthreads();
  }
  short* Tb = (short*)smem;  // [64][72] (144 B row pitch = 9*16, b128-safe)
  int mrd = tid >> 2, ncol = (tid & 3) * 16;
  // --- Q (swapped acc: col c = spatial, rows 4g+r = out-channel) ---
#pragma unroll
  for (int i = 0; i < 2; ++i)
#pragma unroll
    for (int j = 0; j < 2; ++j) {
      float4 b4 = *(const float4*)&bq[n0 + wn * 32 + j * 16 + 4 * g];
      float v0 = (accq[i][j][0] + b4.x) * scaleq;
      float v1 = (accq[i][j][1] + b4.y) * scaleq;
      float v2 = (accq[i][j][2] + b4.z) * scaleq;
      float v3 = (accq[i][j][3] + b4.w) * scaleq;
      *(uint2*)(Tb + (wm * 32 + i * 16 + c) * 72 + wn * 32 + j * 16 + 4 * g) =
          make_uint2(cvt_pk(v0, v1), cvt_pk(v2, v3));
    }
  __syncthreads();
  {
    bf16x8 r0 = *(const bf16x8*)(Tb + mrd * 72 + ncol);
    bf16x8 r1 = *(const bf16x8*)(Tb + mrd * 72 + ncol + 8);
    short* dst = outq + (size_t)(m0 + mrd) * 256 + n0 + ncol;
    *(bf16x8*)dst = r0;
    *(bf16x8*)(dst + 8) = r1;
  }
  __syncthreads();
  // --- K ---
#pragma unroll
  for (int i = 0; i < 2; ++i)
#pragma unroll
    for (int j = 0; j < 2; ++j) {
      float4 b4 = *(const float4*)&bk[n0 + wn * 32 + j * 16 + 4 * g];
      float v0 = acck[i][j][0] + b4.x;
      float v1 = acck[i][j][1] + b4.y;
      float v2 = acck[i][j][2] + b4.z;
      float v3 = acck[i][j][3] + b4.w;
      *(uint2*)(Tb + (wm * 32 + i * 16 + c) * 72 + wn * 32 + j * 16 + 4 * g) =
          make_uint2(cvt_pk(v0, v1), cvt_pk(v2, v3));
    }
  __syncthreads();
  {
    bf16x8 r0 = *(const bf16x8*)(Tb + mrd * 72 + ncol);
    bf16x8 r1 = *(const bf16x8*)(Tb + mrd * 72 + ncol + 8);
    short* dst = outk + (size_t)(m0 + mrd) * 256 + n0 + ncol;
    *(bf16x8*)dst = r0;
    *(bf16x8*)(dst + 8) = r1;
  }
  __syncthreads();
  // --- V (normal acc) -> vt[d][s] ---
#pragma unroll
  for (int i = 0; i < 2; ++i)
#pragma unroll
    for (int j = 0; j < 2; ++j) {
      float bvv = bv[n0 + wn * 32 + j * 16 + c];
      float v0 = accv[i][j][0] + bvv;
      float v1 = accv[i][j][1] + bvv;
      float v2 = accv[i][j][2] + bvv;
      float v3 = accv[i][j][3] + bvv;
      *(uint2*)(Tb + (wn * 32 + j * 16 + c) * 72 + wm * 32 + i * 16 + 4 * g) =
          make_uint2(cvt_pk(v0, v1), cvt_pk(v2, v3));
    }
  __syncthreads();
  {
    bf16x8 r0 = *(const bf16x8*)(Tb + mrd * 72 + ncol);
    bf16x8 r1 = *(const bf16x8*)(Tb + mrd * 72 + ncol + 8);
    short* dst = outvt + (size_t)(bsmp * 256 + n0 + mrd) * 1024 + s0 + ncol;
    *(bf16x8*)dst = r0;
    *(bf16x8*)(dst + 8) = r1;
  }
}

// ---------------- MFMA flash attention (4 waves; pinned structure + XCD swizzle + setprio) --------
#define KSTR 40
#define VSTR 72
#define PSTR 72

__global__ __launch_bounds__(256, 4) void flash_mfma(
    const short* __restrict__ q, const short* __restrict__ k,
    const short* __restrict__ vt, short* __restrict__ out) {
  __shared__ short Ks[2][64 * KSTR];
  __shared__ short Vts[2][32 * VSTR];
  __shared__ short Ps[4 * 32 * PSTR];
  int id = blockIdx.x;
  int swz = (id & 7) * 128 + (id >> 3);   // bijective on [0,1024)
  int bh = swz >> 3, qt = swz & 7;
  int b = bh >> 3, h = bh & 7;
  int tid = threadIdx.x;
  int w = tid >> 6, lane = tid & 63, g = lane >> 4, c = lane & 15;
  short* Psw = Ps + w * 32 * PSTR;
  const size_t qrow0 = (size_t)b * 1024 + qt * 128 + w * 32;
  const int hoff = h * 32;
  bf16x8 aq[2];
#pragma unroll
  for (int mt = 0; mt < 2; ++mt)
    aq[mt] = *(const bf16x8*)(q + (qrow0 + mt * 16 + c) * 256 + hoff + g * 8);
  bf16x8 ones;
#pragma unroll
  for (int i = 0; i < 8; ++i) ones[i] = (short)0x3F80;
  f32x4 o_acc[2][2], accl[2];
#pragma unroll
  for (int mt = 0; mt < 2; ++mt) {
    accl[mt] = (f32x4){0.f, 0.f, 0.f, 0.f};
#pragma unroll
    for (int nt = 0; nt < 2; ++nt) o_acc[mt][nt] = (f32x4){0.f, 0.f, 0.f, 0.f};
  }
  const int kr = tid >> 2, kch = (tid & 3) * 8;
  const int vr = tid >> 3, vch = (tid & 7) * 8;
  const short* kbase = k + ((size_t)b * 1024) * 256 + hoff;
  const short* vbase = vt + (((size_t)b * 8 + h) * 32) * 1024;
  {
    bf16x8 k0 = *(const bf16x8*)(kbase + (size_t)kr * 256 + kch);
    bf16x8 v0 = *(const bf16x8*)(vbase + (size_t)vr * 1024 + vch);
    *(bf16x8*)(&Ks[0][kr * KSTR + kch]) = k0;
    *(bf16x8*)(&Vts[0][vr * VSTR + vch]) = v0;
  }
  __syncthreads();
  int cur = 0;
#pragma unroll 2
  for (int t = 0; t < 16; ++t) {
    bf16x8 kN, vN;
    if (t < 15) {
      kN = *(const bf16x8*)(kbase + (size_t)((t + 1) * 64 + kr) * 256 + kch);
      vN = *(const bf16x8*)(vbase + (size_t)vr * 1024 + (t + 1) * 64 + vch);
    }
    bf16x8 bk4[4];
#pragma unroll
    for (int kt = 0; kt < 4; ++kt)
      bk4[kt] = *(const bf16x8*)(&Ks[cur][(kt * 16 + c) * KSTR + g * 8]);
    f32x4 sc[2][4];
    __builtin_amdgcn_s_setprio(1);
#pragma unroll
    for (int mt = 0; mt < 2; ++mt)
#pragma unroll
      for (int kt = 0; kt < 4; ++kt)
        sc[mt][kt] = __builtin_amdgcn_mfma_f32_16x16x32_bf16(
            bk4[kt], aq[mt], (f32x4){0.f, 0.f, 0.f, 0.f}, 0, 0, 0);
    __builtin_amdgcn_s_setprio(0);
#pragma unroll
    for (int mt = 0; mt < 2; ++mt)
#pragma unroll
      for (int kt = 0; kt < 4; ++kt) {
        float p0 = __builtin_amdgcn_exp2f(sc[mt][kt][0]);
        float p1 = __builtin_amdgcn_exp2f(sc[mt][kt][1]);
        float p2 = __builtin_amdgcn_exp2f(sc[mt][kt][2]);
        float p3 = __builtin_amdgcn_exp2f(sc[mt][kt][3]);
        *(uint2*)(Psw + (mt * 16 + c) * PSTR + kt * 16 + 4 * g) =
            make_uint2(cvt_pk(p0, p1), cvt_pk(p2, p3));
      }
#pragma unroll
    for (int jt = 0; jt < 2; ++jt) {
      bf16x8 av[2], bp[2];
#pragma unroll
      for (int nt = 0; nt < 2; ++nt)
        av[nt] = *(const bf16x8*)(&Vts[cur][(nt * 16 + c) * VSTR + jt * 32 + g * 8]);
#pragma unroll
      for (int mt = 0; mt < 2; ++mt)
        bp[mt] = *(const bf16x8*)(Psw + (mt * 16 + c) * PSTR + jt * 32 + g * 8);
      __builtin_amdgcn_s_setprio(1);
#pragma unroll
      for (int mt = 0; mt < 2; ++mt) {
#pragma unroll
        for (int nt = 0; nt < 2; ++nt)
          o_acc[mt][nt] = __builtin_amdgcn_mfma_f32_16x16x32_bf16(
              av[nt], bp[mt], o_acc[mt][nt], 0, 0, 0);
        accl[mt] = __builtin_amdgcn_mfma_f32_16x16x32_bf16(ones, bp[mt], accl[mt], 0, 0, 0);
      }
      __builtin_amdgcn_s_setprio(0);
    }
    if (t < 15) {
      *(bf16x8*)(&Ks[cur ^ 1][kr * KSTR + kch]) = kN;
      *(bf16x8*)(&Vts[cur ^ 1][vr * VSTR + vch]) = vN;
      __syncthreads();
      cur ^= 1;
    }
  }
#pragma unroll
  for (int mt = 0; mt < 2; ++mt) {
    float linv = 1.0f / accl[mt][0];
#pragma unroll
    for (int nt = 0; nt < 2; ++nt) {
      float v0 = o_acc[mt][nt][0] * linv;
      float v1 = o_acc[mt][nt][1] * linv;
      float v2 = o_acc[mt][nt][2] * linv;
      float v3 = o_acc[mt][nt][3] * linv;
      *(uint2*)(out + (qrow0 + mt * 16 + c) * 256 + hoff + nt * 16 + 4 * g) =
          make_uint2(cvt_pk(v0, v1), cvt_pk(v2, v3));
    }
  }
}

// ---------------- out-projection GEMM (64x64 tiles), m-major grid, reg-prefetch -----------
__global__ __launch_bounds__(256) void gemm_out(
    const short* __restrict__ A, const short* __restrict__ W,
    const float* __restrict__ bias, float* __restrict__ out) {
  __shared__ __align__(16) char smem[10240];
  short* As = (short*)smem;            // 64*40 shorts = 5120 B
  short* Ws = (short*)(smem + 5120);
  int tid = threadIdx.x;
  int m0 = blockIdx.x * 64, n0 = blockIdx.y * 64;
  int w = tid >> 6, lane = tid & 63, g = lane >> 4, c = lane & 15;
  int wm = w >> 1, wn = w & 1;
  int srow = tid >> 2, sk = (tid & 3) * 8;
  f32x4 acc[2][2];
#pragma unroll
  for (int i = 0; i < 2; ++i)
#pragma unroll
    for (int j = 0; j < 2; ++j) acc[i][j] = (f32x4){0.f, 0.f, 0.f, 0.f};
  bf16x8 aR = *(const bf16x8*)(A + (size_t)(m0 + srow) * 256 + sk);
  bf16x8 wR = *(const bf16x8*)(W + (size_t)(n0 + srow) * 256 + sk);
  for (int kb = 0; kb < 8; ++kb) {
    *(bf16x8*)(As + srow * 40 + sk) = aR;
    *(bf16x8*)(Ws + srow * 40 + sk) = wR;
    __syncthreads();
    if (kb < 7) {
      aR = *(const bf16x8*)(A + (size_t)(m0 + srow) * 256 + (kb + 1) * 32 + sk);
      wR = *(const bf16x8*)(W + (size_t)(n0 + srow) * 256 + (kb + 1) * 32 + sk);
    }
    bf16x8 af[2], wf[2];
#pragma unroll
    for (int i = 0; i < 2; ++i)
      af[i] = *(const bf16x8*)(As + (wm * 32 + i * 16 + c) * 40 + g * 8);
#pragma unroll
    for (int j = 0; j < 2; ++j)
      wf[j] = *(const bf16x8*)(Ws + (wn * 32 + j * 16 + c) * 40 + g * 8);
#pragma unroll
    for (int i = 0; i < 2; ++i)
#pragma unroll
      for (int j = 0; j < 2; ++j)
        acc[i][j] = __builtin_amdgcn_mfma_f32_16x16x32_bf16(af[i], wf[j], acc[i][j], 0, 0, 0);
    __syncthreads();
  }
  int bsmp = m0 >> 10, s0 = m0 & 1023;
  float* Tf = (float*)smem;  // [32][68] XOR-swizzled
  for (int half = 0; half < 2; ++half) {
    __syncthreads();
    if (wn == half) {
#pragma unroll
      for (int j = 0; j < 2; ++j) {
        float bvh = bias[n0 + half * 32 + j * 16 + c];
        int nl = j * 16 + c;
#pragma unroll
        for (int i = 0; i < 2; ++i)
#pragma unroll
          for (int r = 0; r < 4; ++r)
            Tf[nl * 68 + ((wm * 32 + i * 16 + 4 * g + r) ^ ((nl & 7) << 2))] =
                acc[i][j][r] + bvh;
      }
    }
    __syncthreads();
    int n = tid >> 3, mc = (tid & 7) * 8;
    float4 v0 = *(const float4*)(Tf + n * 68 + ((mc + 0) ^ ((n & 7) << 2)));
    float4 v1 = *(const float4*)(Tf + n * 68 + ((mc + 4) ^ ((n & 7) << 2)));
    float* dst = out + ((size_t)(bsmp * 256) + n0 + half * 32 + n) * 1024 + s0 + mc;
    *(float4*)dst = v0;
    *(float4*)(dst + 4) = v1;
  }
}

extern "C" void kernel_launch(void* const* d_in, const int* in_sizes, int n_in,
                              void* d_out, int out_size, void* d_ws, size_t ws_size,
                              hipStream_t stream) {
  const float* x   = (const float*)d_in[0];
  const float* wq  = (const float*)d_in[1];
  const float* bq  = (const float*)d_in[2];
  const float* wk  = (const float*)d_in[3];
  const float* bk  = (const float*)d_in[4];
  const float* wv  = (const float*)d_in[5];
  const float* bv  = (const float*)d_in[6];
  const float* wo  = (const float*)d_in[7];
  const float* bo  = (const float*)d_in[8];
  const float* gnw = (const float*)d_in[9];
  const float* gnb = (const float*)d_in[10];
  float* out = (float*)d_out;

  const size_t NE = (size_t)16 * 1024 * 256;  // 4194304
  short* sw  = (short*)d_ws;
  float2* statsp = (float2*)sw;  // 512 partial (S, SS) pairs
  short* qb  = sw + NE;          // bf16, pre-scaled by hd^-0.5*log2e
  short* kb  = sw + 2 * NE;
  short* vtb = sw + 3 * NE;      // bf16 [(b*8+h)*32+d][S]
  short* ao  = sw + 4 * NE;      // bf16 attn out [B*S][C]
  short* wqb = sw + 5 * NE;
  short* wkb = wqb + 65536;
  short* wvb = wkb + 65536;
  short* wob = wvb + 65536;

  const float SCALE_Q = (float)(0.17677669529663689 * 1.4426950408889634);
  dim3 blk(256);
  prep_kernel<<<dim3(640), blk, 0, stream>>>(x, statsp, wq, wk, wv, wo,
                                             wqb, wkb, wvb, wob);
  qkv_mfma<<<dim3(256, 4), blk, 0, stream>>>(x, statsp, gnw, gnb, wqb, wkb, wvb,
                                             bq, bk, bv, qb, kb, vtb, SCALE_Q);
  flash_mfma<<<dim3(1024), blk, 0, stream>>>(qb, kb, vtb, ao);
  gemm_out<<<dim3(256, 4), blk, 0, stream>>>(ao, wob, bo, out);
}